// Round 9
// baseline (285.226 us; speedup 1.0000x reference)
//
#include <hip/hip_runtime.h>
#include <hip/hip_bf16.h>

#define M_N 100000
#define K_F 512
#define N_F 128
#define N_E 1600000
#define NBUK 782           // ceil(100000/128) dst-buckets of 128 nodes
#define CAP 2560           // per-bucket capacity (mean 2046, sd 45 -> +11 sigma)
#define EPB 4096           // edges per k_bin block -> 391 blocks (CU-saturating)

typedef __attribute__((ext_vector_type(8))) short bf16x8;
typedef __attribute__((ext_vector_type(4))) float f32x4;

__device__ __forceinline__ unsigned short f2bf(float f) {
  unsigned u = __float_as_uint(f);
  u += 0x7FFFu + ((u >> 16) & 1u);      // RNE
  return (unsigned short)(u >> 16);
}

__device__ __forceinline__ unsigned pkbf(float a, float b) {
  __hip_bfloat162 h = __float22bfloat162_rn(make_float2(a, b));
  return *(unsigned*)&h;                // v_cvt_pk_bf16_f32
}

// ---------- 1) weight: f32 [512][128] -> bf16 transposed [128][512] ----------
__global__ void k_wt(const float* __restrict__ w, unsigned short* __restrict__ wtb) {
  int idx = blockIdx.x * 256 + threadIdx.x;     // 65536 total
  int k = idx >> 7, n = idx & 127;
  wtb[n * K_F + k] = f2bf(w[idx]);              // w[idx] == w[k][n]
}

// ---------- 2) GEMM: global_load_lds dbuf, BK=32 -> 32KB LDS -> 4 blocks/CU ----------
// Mechanism: the per-iter barrier drains vmcnt(0); with 4 resident blocks the
// drain of one block overlaps compute of the other three (cross-block pipelining).
__global__ __launch_bounds__(256, 4) void k_gemm(const float* __restrict__ A,
                       const unsigned short* __restrict__ Bt,   // [128][512] bf16
                       unsigned short* __restrict__ S) {        // [M][128] bf16
  __shared__ __align__(16) float As[2][128 * 32];               // 2 x 16KB
  const int tid = threadIdx.x;
  const int lane = tid & 63;
  const int wv = tid >> 6;
  const int lr = lane & 15, lq = lane >> 4;
  const int bm0 = blockIdx.x * 128;
  const int wrow = wv * 32;

  const unsigned short* bbase = Bt + (size_t)lr * K_F + lq * 8;

  f32x4 acc[2][8] = {};

  // prologue: stage tile 0 (16KB: 1024 16B-chunks, 4 per thread)
#pragma unroll
  for (int i = 0; i < 4; i++) {
    int idx = i * 256 + tid;
    int r = idx >> 3, c = idx & 7;                 // row, 16B-chunk in row
    int gr = bm0 + r; if (gr > M_N - 1) gr = M_N - 1;
    const float* src = A + (size_t)gr * K_F + 0 + (c ^ (r & 7)) * 4;
    __builtin_amdgcn_global_load_lds(
        (const __attribute__((address_space(1))) void*)src,
        (__attribute__((address_space(3))) void*)&As[0][(i * 256 + wv * 64) * 4],
        16, 0, 0);
  }
  __syncthreads();

#pragma unroll
  for (int t = 0; t < 16; t++) {
    const int cur = t & 1;
    const int k0 = t * 32;

    // B fragments for this K-tile (issued before STAGE)
    bf16x8 pb[8];
#pragma unroll
    for (int n = 0; n < 8; n++)
      pb[n] = *(const bf16x8*)(bbase + (size_t)n * 16 * K_F + k0);

    // stage tile t+1 (fire-and-forget)
    if (t < 15) {
#pragma unroll
      for (int i = 0; i < 4; i++) {
        int idx = i * 256 + tid;
        int r = idx >> 3, c = idx & 7;
        int gr = bm0 + r; if (gr > M_N - 1) gr = M_N - 1;
        const float* src = A + (size_t)gr * K_F + (k0 + 32) + (c ^ (r & 7)) * 4;
        __builtin_amdgcn_global_load_lds(
            (const __attribute__((address_space(1))) void*)src,
            (__attribute__((address_space(3))) void*)&As[cur ^ 1][(i * 256 + wv * 64) * 4],
            16, 0, 0);
      }
    }

    // compute on buf[cur]
#pragma unroll
    for (int m = 0; m < 2; m++) {
      int R = wrow + m * 16 + lr;
      int cb = lq * 2;                    // 16B-chunk index within row (pre-swizzle)
      int sw = R & 7;
      f32x4 f0 = *(const f32x4*)&As[cur][(R * 8 + (cb ^ sw)) * 4];
      f32x4 f1 = *(const f32x4*)&As[cur][(R * 8 + ((cb + 1) ^ sw)) * 4];
      uint4 u;
      u.x = pkbf(f0[0], f0[1]);
      u.y = pkbf(f0[2], f0[3]);
      u.z = pkbf(f1[0], f1[1]);
      u.w = pkbf(f1[2], f1[3]);
      bf16x8 af = *(bf16x8*)&u;
#pragma unroll
      for (int n = 0; n < 8; n++)
        acc[m][n] = __builtin_amdgcn_mfma_f32_16x16x32_bf16(af, pb[n], acc[m][n], 0, 0, 0);
    }
    __syncthreads();
  }

  // epilogue: D layout col=lane&15, row=(lane>>4)*4+j  [measured m89]
#pragma unroll
  for (int m = 0; m < 2; m++)
#pragma unroll
    for (int j = 0; j < 4; j++) {
      int gr = bm0 + wrow + m * 16 + lq * 4 + j;
      if (gr < M_N) {
#pragma unroll
        for (int n = 0; n < 8; n++)
          S[(size_t)gr * N_F + n * 16 + lr] = f2bf(acc[m][n][j]);
      }
    }
}

// ---------- 3) init bucket cursors ----------
__global__ void k_init(int* __restrict__ gcur) {
  int b = blockIdx.x * 256 + threadIdx.x;
  if (b < NBUK) gcur[b] = b * CAP;
}

// ---------- 4) bin edges by dst>>7 with per-block run reservation ----------
__global__ __launch_bounds__(512) void k_bin(const int* __restrict__ src,
                                             const int* __restrict__ dst,
                                             const float* __restrict__ w,
                                             int* __restrict__ gcur,
                                             uint2* __restrict__ ebin) {
  __shared__ int lh[NBUK];
  __shared__ int lb[NBUK];
  const int tid = threadIdx.x;
  const int e0 = blockIdx.x * EPB;
  for (int b = tid; b < NBUK; b += 512) lh[b] = 0;
  __syncthreads();
#pragma unroll
  for (int i = 0; i < EPB / 512; i++) {
    int e = e0 + i * 512 + tid;
    if (e < N_E) atomicAdd(&lh[dst[e] >> 7], 1);
  }
  __syncthreads();
  for (int b = tid; b < NBUK; b += 512) {
    int c = lh[b];
    lb[b] = c ? atomicAdd(&gcur[b], c) : 0;
    lh[b] = 0;                       // reuse as rank cursor
  }
  __syncthreads();
#pragma unroll
  for (int i = 0; i < EPB / 512; i++) {
    int e = e0 + i * 512 + tid;
    if (e < N_E) {
      int d = dst[e];
      int bk = d >> 7;
      int rank = atomicAdd(&lh[bk], 1);
      ebin[lb[bk] + rank] =
          make_uint2(((unsigned)(d & 127) << 17) | (unsigned)src[e],
                     __float_as_uint(w[e]));
    }
  }
}

// ---------- 5) exclusive scan of the 782 bucket counts (1 block) ----------
__global__ void k_scanB(const int* __restrict__ gcur, int* __restrict__ cbase) {
  __shared__ int sm[1024];
  int t = threadIdx.x;
  int v = (t < NBUK) ? (gcur[t] - t * CAP) : 0;
  sm[t] = v;
  __syncthreads();
  for (int off = 1; off < 1024; off <<= 1) {
    int x = sm[t];
    int a = (t >= off) ? sm[t - off] : 0;
    __syncthreads();
    sm[t] = x + a;
    __syncthreads();
  }
  if (t < NBUK) cbase[t] = sm[t] - v;
}

// ---------- 6) per-bucket counting sort -> CSR (contiguous 16KB writes) ----------
__global__ __launch_bounds__(256) void k_csr(const uint2* __restrict__ ebin,
                                             const int* __restrict__ gcur,
                                             const int* __restrict__ cbase,
                                             int2* __restrict__ eidx,
                                             int* __restrict__ rowstart) {
  __shared__ uint2 st[CAP];                 // 20KB staging
  __shared__ int hist[128], excl[129], cur[128];
  const int b = blockIdx.x;
  const int t = threadIdx.x;
  const int cnt = gcur[b] - b * CAP;
  const uint2* eb = ebin + (size_t)b * CAP;

  if (t < 128) hist[t] = 0;
  __syncthreads();
  for (int i = t; i < cnt; i += 256) {
    uint2 e = eb[i];
    st[i] = e;
    atomicAdd(&hist[(e.x >> 17) & 127], 1);   // native ds_add_u32
  }
  __syncthreads();
  // exclusive scan over 128 counters
  if (t < 128) excl[t + 1] = hist[t];
  if (t == 0) excl[0] = 0;
  __syncthreads();
  for (int off = 1; off < 128; off <<= 1) {
    int v = 0;
    if (t < 128) {
      v = excl[t + 1];
      if (t + 1 > off) v += excl[t + 1 - off];
    }
    __syncthreads();
    if (t < 128) excl[t + 1] = v;
    __syncthreads();
  }
  const int base = cbase[b];
  if (t < 128) {
    cur[t] = excl[t];
    int node = b * 128 + t;
    if (node <= M_N) rowstart[node] = base + excl[t];  // b=781,t=32 writes rowstart[M_N]=N_E
  }
  __syncthreads();
  for (int i = t; i < cnt; i += 256) {
    uint2 e = st[i];
    int dl = (e.x >> 17) & 127;
    int r = atomicAdd(&cur[dl], 1);
    eidx[base + r] = make_int2((int)(e.x & 0x1FFFFu), (int)e.y);
  }
}

// ---------- 7) SpMM gather: wave/node, 4 groups x unroll 4 (16 gathers in flight) ----------
__device__ __forceinline__ void fma8(float* acc, float wgt, uint4 v) {
  acc[0] = fmaf(wgt, __uint_as_float(v.x << 16), acc[0]);
  acc[1] = fmaf(wgt, __uint_as_float(v.x & 0xFFFF0000u), acc[1]);
  acc[2] = fmaf(wgt, __uint_as_float(v.y << 16), acc[2]);
  acc[3] = fmaf(wgt, __uint_as_float(v.y & 0xFFFF0000u), acc[3]);
  acc[4] = fmaf(wgt, __uint_as_float(v.z << 16), acc[4]);
  acc[5] = fmaf(wgt, __uint_as_float(v.z & 0xFFFF0000u), acc[5]);
  acc[6] = fmaf(wgt, __uint_as_float(v.w << 16), acc[6]);
  acc[7] = fmaf(wgt, __uint_as_float(v.w & 0xFFFF0000u), acc[7]);
}

__global__ void k_spmm(const unsigned short* __restrict__ S,
                       const int* __restrict__ rowstart,
                       const int2* __restrict__ eidx,
                       float* __restrict__ out) {
  int wid = (blockIdx.x * 256 + threadIdx.x) >> 6;
  int lane = threadIdx.x & 63;
  if (wid >= M_N) return;
  const int g = lane >> 4;          // edge subgroup 0..3
  const int l = lane & 15;          // 16B chunk within the 256B row
  int s = rowstart[wid], e = rowstart[wid + 1];

  float acc[8] = {0.f, 0.f, 0.f, 0.f, 0.f, 0.f, 0.f, 0.f};

  int i = s + g;
  for (; i + 12 < e; i += 16) {
    int2 p0 = eidx[i];
    int2 p1 = eidx[i + 4];
    int2 p2 = eidx[i + 8];
    int2 p3 = eidx[i + 12];
    uint4 v0 = *(const uint4*)(S + (size_t)p0.x * N_F + l * 8);
    uint4 v1 = *(const uint4*)(S + (size_t)p1.x * N_F + l * 8);
    uint4 v2 = *(const uint4*)(S + (size_t)p2.x * N_F + l * 8);
    uint4 v3 = *(const uint4*)(S + (size_t)p3.x * N_F + l * 8);
    fma8(acc, __int_as_float(p0.y), v0);
    fma8(acc, __int_as_float(p1.y), v1);
    fma8(acc, __int_as_float(p2.y), v2);
    fma8(acc, __int_as_float(p3.y), v3);
  }
  for (; i < e; i += 4) {
    int2 p = eidx[i];
    uint4 v = *(const uint4*)(S + (size_t)p.x * N_F + l * 8);
    fma8(acc, __int_as_float(p.y), v);
  }

  // reduce across the 4 groups (lane bits 4,5) + fused ReLU
#pragma unroll
  for (int j = 0; j < 8; j++) {
    acc[j] += __shfl_xor(acc[j], 16, 64);
    acc[j] += __shfl_xor(acc[j], 32, 64);
    acc[j] = fmaxf(acc[j], 0.f);
  }

  // coalesced 512B store from 32 lanes (groups 0,1)
  if (g < 2) {
    float4 r = make_float4(acc[g * 4 + 0], acc[g * 4 + 1], acc[g * 4 + 2], acc[g * 4 + 3]);
    *(float4*)(out + (size_t)wid * N_F + l * 8 + g * 4) = r;
  }
}

extern "C" void kernel_launch(void* const* d_in, const int* in_sizes, int n_in,
                              void* d_out, int out_size, void* d_ws, size_t ws_size,
                              hipStream_t stream) {
  const float* features = (const float*)d_in[0];
  const float* weight   = (const float*)d_in[1];
  const int* edge_src   = (const int*)d_in[2];
  const int* edge_dst   = (const int*)d_in[3];
  const float* edge_w   = (const float*)d_in[4];
  float* out = (float*)d_out;

  // workspace layout (256B-aligned chunks)
  char* ws = (char*)d_ws;
  size_t off = 0;
  unsigned short* support = (unsigned short*)(ws + off); off += (size_t)M_N * N_F * 2;   // 25.6MB
  unsigned short* wtb     = (unsigned short*)(ws + off); off += (size_t)N_F * K_F * 2;   // 128KB
  int* gcur     = (int*)(ws + off); off += 4096;
  int* cbase    = (int*)(ws + off); off += 4096;
  int* rowstart = (int*)(ws + off); off += ((size_t)(M_N + 1) * 4 + 255) / 256 * 256;
  uint2* ebin   = (uint2*)(ws + off); off += ((size_t)NBUK * CAP + 64) * 8;              // ~16MB
  int2* eidx    = (int2*)(ws + off); off += (size_t)N_E * 8;                             // 12.8MB

  k_wt<<<256, 256, 0, stream>>>(weight, wtb);
  k_gemm<<<(M_N + 127) / 128, 256, 0, stream>>>(features, wtb, support);
  k_init<<<4, 256, 0, stream>>>(gcur);
  k_bin<<<(N_E + EPB - 1) / EPB, 512, 0, stream>>>(edge_src, edge_dst, edge_w, gcur, ebin);
  k_scanB<<<1, 1024, 0, stream>>>(gcur, cbase);
  k_csr<<<NBUK, 256, 0, stream>>>(ebin, gcur, cbase, eidx, rowstart);
  k_spmm<<<(M_N * 64 + 255) / 256, 256, 0, stream>>>(support, rowstart, eidx, out);
}

// Round 10
// 189.819 us; speedup vs baseline: 1.5026x; 1.5026x over previous
//
#include <hip/hip_runtime.h>
#include <hip/hip_bf16.h>

#define M_N 100000
#define K_F 512
#define N_F 128
#define N_E 1600000
#define NBUK 782           // ceil(100000/128) dst-buckets of 128 nodes
#define CAP 2560           // per-bucket capacity (mean 2046, sd 45 -> +11 sigma)
#define EPB 4096           // edges per k_bin block -> 391 blocks

typedef __attribute__((ext_vector_type(8))) short bf16x8;
typedef __attribute__((ext_vector_type(4))) float f32x4;

__device__ __forceinline__ unsigned short f2bf(float f) {
  unsigned u = __float_as_uint(f);
  u += 0x7FFFu + ((u >> 16) & 1u);      // RNE
  return (unsigned short)(u >> 16);
}

__device__ __forceinline__ unsigned pkbf(float a, float b) {
  __hip_bfloat162 h = __float22bfloat162_rn(make_float2(a, b));
  return *(unsigned*)&h;                // v_cvt_pk_bf16_f32
}

// ---------- 1) weight: f32 [512][128] -> bf16 transposed [128][512] ----------
__global__ void k_wt(const float* __restrict__ w, unsigned short* __restrict__ wtb) {
  int idx = blockIdx.x * 256 + threadIdx.x;     // 65536 total
  int k = idx >> 7, n = idx & 127;
  wtb[n * K_F + k] = f2bf(w[idx]);              // w[idx] == w[k][n]
}

// ---------- 2) GEMM: 3-buffer depth-2 pipeline, counted vmcnt (T3+T4) ----------
// Per tile (BK=64): A 128x64 f32 (32KB) + B 128x64 bf16 (16KB) staged via
// global_load_lds (12 loads/thread). Loop: s_waitcnt vmcnt(12) [tile t done,
// t+1/t+2 in flight - NEVER drained to 0] -> s_barrier -> stage(t+2) ->
// compute(t). 144KB LDS -> 1 block/CU; launch_bounds(256,1) -> no reg spill.
__global__ __launch_bounds__(256, 1) void k_gemm(const float* __restrict__ A,
                       const unsigned short* __restrict__ Bt,   // [128][512] bf16
                       unsigned short* __restrict__ S) {        // [M][128] bf16
  __shared__ __align__(16) float As[3][128 * 64];               // 3 x 32KB
  __shared__ __align__(16) unsigned short Bs[3][128 * 64];      // 3 x 16KB
  const int tid = threadIdx.x;
  const int lane = tid & 63;
  const int wv = tid >> 6;
  const int lr = lane & 15, lq = lane >> 4;
  const int bm0 = blockIdx.x * 128;
  const int wrow = wv * 32;

  f32x4 acc[2][8] = {};

#define STAGE(T, BUF)                                                          \
  do {                                                                         \
    _Pragma("unroll") for (int i = 0; i < 8; i++) {                            \
      int idx = i * 256 + tid;                                                 \
      int r = idx >> 4, c = idx & 15;                                          \
      int gr = bm0 + r; if (gr > M_N - 1) gr = M_N - 1;                        \
      const float* srcp = A + (size_t)gr * K_F + (T) * 64 + (c ^ (r & 7)) * 4; \
      __builtin_amdgcn_global_load_lds(                                        \
          (const __attribute__((address_space(1))) void*)srcp,                 \
          (__attribute__((address_space(3))) void*)&As[BUF][(i * 256 + wv * 64) * 4], \
          16, 0, 0);                                                           \
    }                                                                          \
    _Pragma("unroll") for (int i = 0; i < 4; i++) {                            \
      int idx = i * 256 + tid;                                                 \
      int n = idx >> 3, c = idx & 7;                                           \
      const unsigned short* srcb = Bt + (size_t)n * K_F + (T) * 64 + (c ^ (n & 7)) * 8; \
      __builtin_amdgcn_global_load_lds(                                        \
          (const __attribute__((address_space(1))) void*)srcb,                 \
          (__attribute__((address_space(3))) void*)&Bs[BUF][(i * 256 + wv * 64) * 8], \
          16, 0, 0);                                                           \
    }                                                                          \
  } while (0)

  STAGE(0, 0);
  STAGE(1, 1);

#pragma unroll
  for (int t = 0; t < 8; t++) {
    if (t < 7) asm volatile("s_waitcnt vmcnt(12)" ::: "memory");
    else       asm volatile("s_waitcnt vmcnt(0)" ::: "memory");
    __builtin_amdgcn_sched_barrier(0);
    __builtin_amdgcn_s_barrier();
    __builtin_amdgcn_sched_barrier(0);
    if (t < 6) {
      switch ((t + 2) % 3) {          // compile-time under full unroll
        case 0: STAGE(t + 2, 0); break;
        case 1: STAGE(t + 2, 1); break;
        default: STAGE(t + 2, 2); break;
      }
    }
    const int cb_ = t % 3;
#pragma unroll
    for (int ks = 0; ks < 2; ks++) {
      bf16x8 pb[8];
#pragma unroll
      for (int n = 0; n < 8; n++) {
        int r = n * 16 + lr;
        int cc = (ks * 4 + lq) ^ (r & 7);
        pb[n] = *(const bf16x8*)&Bs[cb_][r * 64 + cc * 8];
      }
#pragma unroll
      for (int m = 0; m < 2; m++) {
        int R = wrow + m * 16 + lr;
        int cb = ks * 8 + lq * 2, sw = R & 7;
        f32x4 f0 = *(const f32x4*)&As[cb_][R * 64 + ((cb) ^ sw) * 4];
        f32x4 f1 = *(const f32x4*)&As[cb_][R * 64 + ((cb + 1) ^ sw) * 4];
        uint4 u;
        u.x = pkbf(f0[0], f0[1]);
        u.y = pkbf(f0[2], f0[3]);
        u.z = pkbf(f1[0], f1[1]);
        u.w = pkbf(f1[2], f1[3]);
        bf16x8 af = *(bf16x8*)&u;
#pragma unroll
        for (int n = 0; n < 8; n++)
          acc[m][n] = __builtin_amdgcn_mfma_f32_16x16x32_bf16(af, pb[n], acc[m][n], 0, 0, 0);
      }
    }
  }
#undef STAGE

  // epilogue: D layout col=lane&15, row=(lane>>4)*4+j  [measured m89]
#pragma unroll
  for (int m = 0; m < 2; m++)
#pragma unroll
    for (int j = 0; j < 4; j++) {
      int gr = bm0 + wrow + m * 16 + lq * 4 + j;
      if (gr < M_N) {
#pragma unroll
        for (int n = 0; n < 8; n++)
          S[(size_t)gr * N_F + n * 16 + lr] = f2bf(acc[m][n][j]);
      }
    }
}

// ---------- 3) init bucket cursors ----------
__global__ void k_init(int* __restrict__ gcur) {
  int b = blockIdx.x * 256 + threadIdx.x;
  if (b < NBUK) gcur[b] = b * CAP;
}

// ---------- 4) bin edges by dst>>7 with per-block run reservation ----------
__global__ __launch_bounds__(512) void k_bin(const int* __restrict__ src,
                                             const int* __restrict__ dst,
                                             const float* __restrict__ w,
                                             int* __restrict__ gcur,
                                             uint2* __restrict__ ebin) {
  __shared__ int lh[NBUK];
  __shared__ int lb[NBUK];
  const int tid = threadIdx.x;
  const int e0 = blockIdx.x * EPB;
  for (int b = tid; b < NBUK; b += 512) lh[b] = 0;
  __syncthreads();
#pragma unroll
  for (int i = 0; i < EPB / 512; i++) {
    int e = e0 + i * 512 + tid;
    if (e < N_E) atomicAdd(&lh[dst[e] >> 7], 1);
  }
  __syncthreads();
  for (int b = tid; b < NBUK; b += 512) {
    int c = lh[b];
    lb[b] = c ? atomicAdd(&gcur[b], c) : 0;
    lh[b] = 0;                       // reuse as rank cursor
  }
  __syncthreads();
#pragma unroll
  for (int i = 0; i < EPB / 512; i++) {
    int e = e0 + i * 512 + tid;
    if (e < N_E) {
      int d = dst[e];
      int bk = d >> 7;
      int rank = atomicAdd(&lh[bk], 1);
      ebin[lb[bk] + rank] =
          make_uint2(((unsigned)(d & 127) << 17) | (unsigned)src[e],
                     __float_as_uint(w[e]));
    }
  }
}

// ---------- 5) exclusive scan of the 782 bucket counts (1 block) ----------
__global__ void k_scanB(const int* __restrict__ gcur, int* __restrict__ cbase) {
  __shared__ int sm[1024];
  int t = threadIdx.x;
  int v = (t < NBUK) ? (gcur[t] - t * CAP) : 0;
  sm[t] = v;
  __syncthreads();
  for (int off = 1; off < 1024; off <<= 1) {
    int x = sm[t];
    int a = (t >= off) ? sm[t - off] : 0;
    __syncthreads();
    sm[t] = x + a;
    __syncthreads();
  }
  if (t < NBUK) cbase[t] = sm[t] - v;
}

// ---------- 6) per-bucket counting sort -> CSR (contiguous 16KB writes) ----------
__global__ __launch_bounds__(256) void k_csr(const uint2* __restrict__ ebin,
                                             const int* __restrict__ gcur,
                                             const int* __restrict__ cbase,
                                             int2* __restrict__ eidx,
                                             int* __restrict__ rowstart) {
  __shared__ uint2 st[CAP];                 // 20KB staging
  __shared__ int hist[128], excl[129], cur[128];
  const int b = blockIdx.x;
  const int t = threadIdx.x;
  const int cnt = gcur[b] - b * CAP;
  const uint2* eb = ebin + (size_t)b * CAP;

  if (t < 128) hist[t] = 0;
  __syncthreads();
  for (int i = t; i < cnt; i += 256) {
    uint2 e = eb[i];
    st[i] = e;
    atomicAdd(&hist[(e.x >> 17) & 127], 1);   // native ds_add_u32
  }
  __syncthreads();
  // exclusive scan over 128 counters
  if (t < 128) excl[t + 1] = hist[t];
  if (t == 0) excl[0] = 0;
  __syncthreads();
  for (int off = 1; off < 128; off <<= 1) {
    int v = 0;
    if (t < 128) {
      v = excl[t + 1];
      if (t + 1 > off) v += excl[t + 1 - off];
    }
    __syncthreads();
    if (t < 128) excl[t + 1] = v;
    __syncthreads();
  }
  const int base = cbase[b];
  if (t < 128) {
    cur[t] = excl[t];
    int node = b * 128 + t;
    if (node <= M_N) rowstart[node] = base + excl[t];  // b=781,t=32 writes rowstart[M_N]=N_E
  }
  __syncthreads();
  for (int i = t; i < cnt; i += 256) {
    uint2 e = st[i];
    int dl = (e.x >> 17) & 127;
    int r = atomicAdd(&cur[dl], 1);
    eidx[base + r] = make_int2((int)(e.x & 0x1FFFFu), (int)e.y);
  }
}

// ---------- 7) SpMM gather: wave/node, 4 groups x unroll 4 (16 gathers in flight) ----------
__device__ __forceinline__ void fma8(float* acc, float wgt, uint4 v) {
  acc[0] = fmaf(wgt, __uint_as_float(v.x << 16), acc[0]);
  acc[1] = fmaf(wgt, __uint_as_float(v.x & 0xFFFF0000u), acc[1]);
  acc[2] = fmaf(wgt, __uint_as_float(v.y << 16), acc[2]);
  acc[3] = fmaf(wgt, __uint_as_float(v.y & 0xFFFF0000u), acc[3]);
  acc[4] = fmaf(wgt, __uint_as_float(v.z << 16), acc[4]);
  acc[5] = fmaf(wgt, __uint_as_float(v.z & 0xFFFF0000u), acc[5]);
  acc[6] = fmaf(wgt, __uint_as_float(v.w << 16), acc[6]);
  acc[7] = fmaf(wgt, __uint_as_float(v.w & 0xFFFF0000u), acc[7]);
}

__global__ void k_spmm(const unsigned short* __restrict__ S,
                       const int* __restrict__ rowstart,
                       const int2* __restrict__ eidx,
                       float* __restrict__ out) {
  int wid = (blockIdx.x * 256 + threadIdx.x) >> 6;
  int lane = threadIdx.x & 63;
  if (wid >= M_N) return;
  const int g = lane >> 4;          // edge subgroup 0..3
  const int l = lane & 15;          // 16B chunk within the 256B row
  int s = rowstart[wid], e = rowstart[wid + 1];

  float acc[8] = {0.f, 0.f, 0.f, 0.f, 0.f, 0.f, 0.f, 0.f};

  int i = s + g;
  for (; i + 12 < e; i += 16) {
    int2 p0 = eidx[i];
    int2 p1 = eidx[i + 4];
    int2 p2 = eidx[i + 8];
    int2 p3 = eidx[i + 12];
    uint4 v0 = *(const uint4*)(S + (size_t)p0.x * N_F + l * 8);
    uint4 v1 = *(const uint4*)(S + (size_t)p1.x * N_F + l * 8);
    uint4 v2 = *(const uint4*)(S + (size_t)p2.x * N_F + l * 8);
    uint4 v3 = *(const uint4*)(S + (size_t)p3.x * N_F + l * 8);
    fma8(acc, __int_as_float(p0.y), v0);
    fma8(acc, __int_as_float(p1.y), v1);
    fma8(acc, __int_as_float(p2.y), v2);
    fma8(acc, __int_as_float(p3.y), v3);
  }
  for (; i < e; i += 4) {
    int2 p = eidx[i];
    uint4 v = *(const uint4*)(S + (size_t)p.x * N_F + l * 8);
    fma8(acc, __int_as_float(p.y), v);
  }

  // reduce across the 4 groups (lane bits 4,5) + fused ReLU
#pragma unroll
  for (int j = 0; j < 8; j++) {
    acc[j] += __shfl_xor(acc[j], 16, 64);
    acc[j] += __shfl_xor(acc[j], 32, 64);
    acc[j] = fmaxf(acc[j], 0.f);
  }

  // coalesced 512B store from 32 lanes (groups 0,1)
  if (g < 2) {
    float4 r = make_float4(acc[g * 4 + 0], acc[g * 4 + 1], acc[g * 4 + 2], acc[g * 4 + 3]);
    *(float4*)(out + (size_t)wid * N_F + l * 8 + g * 4) = r;
  }
}

extern "C" void kernel_launch(void* const* d_in, const int* in_sizes, int n_in,
                              void* d_out, int out_size, void* d_ws, size_t ws_size,
                              hipStream_t stream) {
  const float* features = (const float*)d_in[0];
  const float* weight   = (const float*)d_in[1];
  const int* edge_src   = (const int*)d_in[2];
  const int* edge_dst   = (const int*)d_in[3];
  const float* edge_w   = (const float*)d_in[4];
  float* out = (float*)d_out;

  // workspace layout (256B-aligned chunks)
  char* ws = (char*)d_ws;
  size_t off = 0;
  unsigned short* support = (unsigned short*)(ws + off); off += (size_t)M_N * N_F * 2;   // 25.6MB
  unsigned short* wtb     = (unsigned short*)(ws + off); off += (size_t)N_F * K_F * 2;   // 128KB
  int* gcur     = (int*)(ws + off); off += 4096;
  int* cbase    = (int*)(ws + off); off += 4096;
  int* rowstart = (int*)(ws + off); off += ((size_t)(M_N + 1) * 4 + 255) / 256 * 256;
  uint2* ebin   = (uint2*)(ws + off); off += ((size_t)NBUK * CAP + 64) * 8;              // ~16MB
  int2* eidx    = (int2*)(ws + off); off += (size_t)N_E * 8;                             // 12.8MB

  k_wt<<<256, 256, 0, stream>>>(weight, wtb);
  k_gemm<<<(M_N + 127) / 128, 256, 0, stream>>>(features, wtb, support);
  k_init<<<4, 256, 0, stream>>>(gcur);
  k_bin<<<(N_E + EPB - 1) / EPB, 512, 0, stream>>>(edge_src, edge_dst, edge_w, gcur, ebin);
  k_scanB<<<1, 1024, 0, stream>>>(gcur, cbase);
  k_csr<<<NBUK, 256, 0, stream>>>(ebin, gcur, cbase, eidx, rowstart);
  k_spmm<<<(M_N * 64 + 255) / 256, 256, 0, stream>>>(support, rowstart, eidx, out);
}

// Round 11
// 175.965 us; speedup vs baseline: 1.6209x; 1.0787x over previous
//
#include <hip/hip_runtime.h>
#include <hip/hip_bf16.h>

#define M_N 100000
#define K_F 512
#define N_F 128
#define N_E 1600000
#define NBUK 782           // ceil(100000/128) dst-buckets of 128 nodes
#define CAP 2560           // per-bucket capacity (mean 2046, sd 45 -> +11 sigma)
#define EPB 8192           // edges per k_bin block -> 196 blocks, runs ~10.5 edges

typedef __attribute__((ext_vector_type(8))) short bf16x8;
typedef __attribute__((ext_vector_type(4))) float f32x4;

__device__ __forceinline__ unsigned short f2bf(float f) {
  unsigned u = __float_as_uint(f);
  u += 0x7FFFu + ((u >> 16) & 1u);      // RNE
  return (unsigned short)(u >> 16);
}

__device__ __forceinline__ unsigned pkbf(float a, float b) {
  __hip_bfloat162 h = __float22bfloat162_rn(make_float2(a, b));
  return *(unsigned*)&h;                // v_cvt_pk_bf16_f32
}

// ---------- 1) weight f32[512][128] -> bf16^T [128][512]; + init bucket cursors ----------
__global__ void k_wt(const float* __restrict__ w, unsigned short* __restrict__ wtb,
                     int* __restrict__ gcur) {
  int idx = blockIdx.x * 256 + threadIdx.x;     // 65536 total
  if (idx < NBUK) gcur[idx] = idx * CAP;
  int k = idx >> 7, n = idx & 127;
  wtb[n * K_F + k] = f2bf(w[idx]);              // w[idx] == w[k][n]
}

// ---------- 2) GEMM: 3-buffer depth-2 pipeline, counted vmcnt (T3+T4) ----------
// Per tile (BK=64): A 128x64 f32 (32KB) + B 128x64 bf16 (16KB) staged via
// global_load_lds (12 loads/thread). Loop: s_waitcnt vmcnt(12) [tile t done,
// t+1/t+2 in flight - NEVER drained to 0] -> s_barrier -> stage(t+2) ->
// compute(t). 144KB LDS -> 1 block/CU; launch_bounds(256,1) -> no reg spill.
__global__ __launch_bounds__(256, 1) void k_gemm(const float* __restrict__ A,
                       const unsigned short* __restrict__ Bt,   // [128][512] bf16
                       unsigned short* __restrict__ S) {        // [M][128] bf16
  __shared__ __align__(16) float As[3][128 * 64];               // 3 x 32KB
  __shared__ __align__(16) unsigned short Bs[3][128 * 64];      // 3 x 16KB
  const int tid = threadIdx.x;
  const int lane = tid & 63;
  const int wv = tid >> 6;
  const int lr = lane & 15, lq = lane >> 4;
  const int bm0 = blockIdx.x * 128;
  const int wrow = wv * 32;

  f32x4 acc[2][8] = {};

#define STAGE(T, BUF)                                                          \
  do {                                                                         \
    _Pragma("unroll") for (int i = 0; i < 8; i++) {                            \
      int idx = i * 256 + tid;                                                 \
      int r = idx >> 4, c = idx & 15;                                          \
      int gr = bm0 + r; if (gr > M_N - 1) gr = M_N - 1;                        \
      const float* srcp = A + (size_t)gr * K_F + (T) * 64 + (c ^ (r & 7)) * 4; \
      __builtin_amdgcn_global_load_lds(                                        \
          (const __attribute__((address_space(1))) void*)srcp,                 \
          (__attribute__((address_space(3))) void*)&As[BUF][(i * 256 + wv * 64) * 4], \
          16, 0, 0);                                                           \
    }                                                                          \
    _Pragma("unroll") for (int i = 0; i < 4; i++) {                            \
      int idx = i * 256 + tid;                                                 \
      int n = idx >> 3, c = idx & 7;                                           \
      const unsigned short* srcb = Bt + (size_t)n * K_F + (T) * 64 + (c ^ (n & 7)) * 8; \
      __builtin_amdgcn_global_load_lds(                                        \
          (const __attribute__((address_space(1))) void*)srcb,                 \
          (__attribute__((address_space(3))) void*)&Bs[BUF][(i * 256 + wv * 64) * 8], \
          16, 0, 0);                                                           \
    }                                                                          \
  } while (0)

  STAGE(0, 0);
  STAGE(1, 1);

#pragma unroll
  for (int t = 0; t < 8; t++) {
    if (t < 7) asm volatile("s_waitcnt vmcnt(12)" ::: "memory");
    else       asm volatile("s_waitcnt vmcnt(0)" ::: "memory");
    __builtin_amdgcn_sched_barrier(0);
    __builtin_amdgcn_s_barrier();
    __builtin_amdgcn_sched_barrier(0);
    if (t < 6) {
      switch ((t + 2) % 3) {          // compile-time under full unroll
        case 0: STAGE(t + 2, 0); break;
        case 1: STAGE(t + 2, 1); break;
        default: STAGE(t + 2, 2); break;
      }
    }
    const int cb_ = t % 3;
#pragma unroll
    for (int ks = 0; ks < 2; ks++) {
      bf16x8 pb[8];
#pragma unroll
      for (int n = 0; n < 8; n++) {
        int r = n * 16 + lr;
        int cc = (ks * 4 + lq) ^ (r & 7);
        pb[n] = *(const bf16x8*)&Bs[cb_][r * 64 + cc * 8];
      }
#pragma unroll
      for (int m = 0; m < 2; m++) {
        int R = wrow + m * 16 + lr;
        int cb = ks * 8 + lq * 2, sw = R & 7;
        f32x4 f0 = *(const f32x4*)&As[cb_][R * 64 + ((cb) ^ sw) * 4];
        f32x4 f1 = *(const f32x4*)&As[cb_][R * 64 + ((cb + 1) ^ sw) * 4];
        uint4 u;
        u.x = pkbf(f0[0], f0[1]);
        u.y = pkbf(f0[2], f0[3]);
        u.z = pkbf(f1[0], f1[1]);
        u.w = pkbf(f1[2], f1[3]);
        bf16x8 af = *(bf16x8*)&u;
#pragma unroll
        for (int n = 0; n < 8; n++)
          acc[m][n] = __builtin_amdgcn_mfma_f32_16x16x32_bf16(af, pb[n], acc[m][n], 0, 0, 0);
      }
    }
  }
#undef STAGE

  // epilogue: D layout col=lane&15, row=(lane>>4)*4+j  [measured m89]
#pragma unroll
  for (int m = 0; m < 2; m++)
#pragma unroll
    for (int j = 0; j < 4; j++) {
      int gr = bm0 + wrow + m * 16 + lq * 4 + j;
      if (gr < M_N) {
#pragma unroll
        for (int n = 0; n < 8; n++)
          S[(size_t)gr * N_F + n * 16 + lr] = f2bf(acc[m][n][j]);
      }
    }
}

// ---------- 3) bin edges by dst>>7 with per-block run reservation ----------
// All writes to an ebin line come from ONE block in contiguous runs ->
// ~full-line writebacks (fixes partial-line RMW of direct CSR scatter).
__global__ __launch_bounds__(512) void k_bin(const int* __restrict__ src,
                                             const int* __restrict__ dst,
                                             const float* __restrict__ w,
                                             int* __restrict__ gcur,
                                             uint2* __restrict__ ebin) {
  __shared__ int lh[NBUK];
  __shared__ int lb[NBUK];
  const int tid = threadIdx.x;
  const int e0 = blockIdx.x * EPB;
  for (int b = tid; b < NBUK; b += 512) lh[b] = 0;
  __syncthreads();
#pragma unroll
  for (int i = 0; i < EPB / 512; i++) {
    int e = e0 + i * 512 + tid;
    if (e < N_E) atomicAdd(&lh[dst[e] >> 7], 1);
  }
  __syncthreads();
  for (int b = tid; b < NBUK; b += 512) {
    int c = lh[b];
    lb[b] = c ? atomicAdd(&gcur[b], c) : 0;
    lh[b] = 0;                       // reuse as rank cursor
  }
  __syncthreads();
#pragma unroll
  for (int i = 0; i < EPB / 512; i++) {
    int e = e0 + i * 512 + tid;
    if (e < N_E) {
      int d = dst[e];
      int bk = d >> 7;
      int rank = atomicAdd(&lh[bk], 1);
      ebin[lb[bk] + rank] =
          make_uint2(((unsigned)(d & 127) << 17) | (unsigned)src[e],
                     __float_as_uint(w[e]));
    }
  }
}

// ---------- 4) fused bucket sort + SpMM gather + ReLU ----------
// Block = one 128-node bucket. Edges -> regs -> LDS counting sort by dst-low7
// (k_csr machinery, kept local: no eidx/rowstart global round-trip). Then
// 8 waves x 16 nodes: proven 4x16-lane gather, descriptors from LDS.
__device__ __forceinline__ void fma8(float* acc, float wgt, uint4 v) {
  acc[0] = fmaf(wgt, __uint_as_float(v.x << 16), acc[0]);
  acc[1] = fmaf(wgt, __uint_as_float(v.x & 0xFFFF0000u), acc[1]);
  acc[2] = fmaf(wgt, __uint_as_float(v.y << 16), acc[2]);
  acc[3] = fmaf(wgt, __uint_as_float(v.y & 0xFFFF0000u), acc[3]);
  acc[4] = fmaf(wgt, __uint_as_float(v.z << 16), acc[4]);
  acc[5] = fmaf(wgt, __uint_as_float(v.z & 0xFFFF0000u), acc[5]);
  acc[6] = fmaf(wgt, __uint_as_float(v.w << 16), acc[6]);
  acc[7] = fmaf(wgt, __uint_as_float(v.w & 0xFFFF0000u), acc[7]);
}

__global__ __launch_bounds__(512) void k_bspmm(const unsigned short* __restrict__ S,
                                               const int* __restrict__ gcur,
                                               const uint2* __restrict__ ebin,
                                               float* __restrict__ out) {
  __shared__ uint2 srt[CAP];                 // 20KB sorted edges
  __shared__ int hist[128], excl[129], cur[128];
  const int b = blockIdx.x;
  const int t = threadIdx.x;
  const int cnt = gcur[b] - b * CAP;
  const uint2* eb = ebin + (size_t)b * CAP;

  if (t < 128) hist[t] = 0;
  __syncthreads();

  // edges -> registers (static 5-slot, CAP/512 = 5)
  uint2 er[5];
  int have = 0;
#pragma unroll
  for (int j = 0; j < 5; j++) {
    int i = j * 512 + t;
    if (i < cnt) { er[j] = eb[i]; have = j + 1; }
  }
#pragma unroll
  for (int j = 0; j < 5; j++)
    if (j < have) atomicAdd(&hist[(er[j].x >> 17) & 127], 1);   // ds_add_u32
  __syncthreads();

  // exclusive scan over 128 counters
  if (t < 128) excl[t + 1] = hist[t];
  if (t == 0) excl[0] = 0;
  __syncthreads();
  for (int off = 1; off < 128; off <<= 1) {
    int v = 0;
    if (t < 128) {
      v = excl[t + 1];
      if (t + 1 > off) v += excl[t + 1 - off];
    }
    __syncthreads();
    if (t < 128) excl[t + 1] = v;
    __syncthreads();
  }
  if (t < 128) cur[t] = excl[t];
  __syncthreads();

  // scatter into sorted LDS array
#pragma unroll
  for (int j = 0; j < 5; j++)
    if (j < have) {
      int dl = (er[j].x >> 17) & 127;
      int r = atomicAdd(&cur[dl], 1);
      srt[r] = er[j];
    }
  __syncthreads();

  // gather: wave wv owns nodes [wv*16, +16)
  const int lane = t & 63, wv = t >> 6;
  const int g = lane >> 4;            // edge subgroup 0..3
  const int l = lane & 15;            // 16B chunk within the 256B row
  for (int nn = 0; nn < 16; nn++) {
    const int ln = wv * 16 + nn;      // local node
    const int s = excl[ln], e = excl[ln + 1];
    float acc[8] = {0.f, 0.f, 0.f, 0.f, 0.f, 0.f, 0.f, 0.f};
    int i = s + g;
    for (; i + 4 < e; i += 8) {       // 2 gathers in flight per group (8/wave)
      uint2 p0 = srt[i];
      uint2 p1 = srt[i + 4];
      uint4 v0 = *(const uint4*)(S + (size_t)(p0.x & 0x1FFFFu) * N_F + l * 8);
      uint4 v1 = *(const uint4*)(S + (size_t)(p1.x & 0x1FFFFu) * N_F + l * 8);
      fma8(acc, __uint_as_float(p0.y), v0);
      fma8(acc, __uint_as_float(p1.y), v1);
    }
    if (i < e) {
      uint2 p = srt[i];
      uint4 v = *(const uint4*)(S + (size_t)(p.x & 0x1FFFFu) * N_F + l * 8);
      fma8(acc, __uint_as_float(p.y), v);
    }
#pragma unroll
    for (int j = 0; j < 8; j++) {
      acc[j] += __shfl_xor(acc[j], 16, 64);
      acc[j] += __shfl_xor(acc[j], 32, 64);
      acc[j] = fmaxf(acc[j], 0.f);
    }
    const int node = b * 128 + ln;
    if (g < 2 && node < M_N) {
      float4 r = make_float4(acc[g * 4 + 0], acc[g * 4 + 1],
                             acc[g * 4 + 2], acc[g * 4 + 3]);
      *(float4*)(out + (size_t)node * N_F + l * 8 + g * 4) = r;
    }
  }
}

extern "C" void kernel_launch(void* const* d_in, const int* in_sizes, int n_in,
                              void* d_out, int out_size, void* d_ws, size_t ws_size,
                              hipStream_t stream) {
  const float* features = (const float*)d_in[0];
  const float* weight   = (const float*)d_in[1];
  const int* edge_src   = (const int*)d_in[2];
  const int* edge_dst   = (const int*)d_in[3];
  const float* edge_w   = (const float*)d_in[4];
  float* out = (float*)d_out;

  // workspace layout (256B-aligned chunks)
  char* ws = (char*)d_ws;
  size_t off = 0;
  unsigned short* support = (unsigned short*)(ws + off); off += (size_t)M_N * N_F * 2;   // 25.6MB
  unsigned short* wtb     = (unsigned short*)(ws + off); off += (size_t)N_F * K_F * 2;   // 128KB
  int* gcur   = (int*)(ws + off); off += 4096;
  uint2* ebin = (uint2*)(ws + off); off += ((size_t)NBUK * CAP + 64) * 8;                // ~16MB

  k_wt<<<256, 256, 0, stream>>>(weight, wtb, gcur);
  k_gemm<<<(M_N + 127) / 128, 256, 0, stream>>>(features, wtb, support);
  k_bin<<<(N_E + EPB - 1) / EPB, 512, 0, stream>>>(edge_src, edge_dst, edge_w, gcur, ebin);
  k_bspmm<<<NBUK, 512, 0, stream>>>(support, gcur, ebin, out);
}

// Round 12
// 170.156 us; speedup vs baseline: 1.6763x; 1.0341x over previous
//
#include <hip/hip_runtime.h>
#include <hip/hip_bf16.h>

#define M_N 100000
#define K_F 512
#define N_F 128
#define N_E 1600000
#define NBUK 782           // ceil(100000/128) dst-buckets of 128 nodes
#define CAP 2560           // per-bucket capacity (mean 2046, sd 45 -> +11 sigma)
#define EPB 8192           // edges per k_bin block -> 196 blocks

typedef __attribute__((ext_vector_type(8))) short bf16x8;
typedef __attribute__((ext_vector_type(4))) float f32x4;

__device__ __forceinline__ unsigned short f2bf(float f) {
  unsigned u = __float_as_uint(f);
  u += 0x7FFFu + ((u >> 16) & 1u);      // RNE
  return (unsigned short)(u >> 16);
}

__device__ __forceinline__ unsigned pkbf(float a, float b) {
  __hip_bfloat162 h = __float22bfloat162_rn(make_float2(a, b));
  return *(unsigned*)&h;                // v_cvt_pk_bf16_f32
}

// ---------- 1) weight f32[512][128] -> bf16^T [128][512]; + init bucket cursors ----------
__global__ void k_wt(const float* __restrict__ w, unsigned short* __restrict__ wtb,
                     int* __restrict__ gcur) {
  int idx = blockIdx.x * 256 + threadIdx.x;     // 65536 total
  if (idx < NBUK) gcur[idx] = idx * CAP;
  int k = idx >> 7, n = idx & 127;
  wtb[n * K_F + k] = f2bf(w[idx]);              // w[idx] == w[k][n]
}

// ---------- 2) GEMM: BK=32, 3-buffer depth-2 counted-vmcnt pipeline, 2 blocks/CU ----------
// Per tile: A 128x32 f32 (16KB) + B 128x32 bf16 (8KB) via global_load_lds
// (6 loads/thread). Loop: vmcnt(6) [tile t done, t+1/t+2 in flight, never 0]
// -> barrier -> STAGE(t+2) -> compute(t). LDS 72KB -> 2 blocks/CU: backfill
// kills the 31% dispatch-tail waste and the co-resident block covers stalls.
__global__ __launch_bounds__(256, 2) void k_gemm(const float* __restrict__ A,
                       const unsigned short* __restrict__ Bt,   // [128][512] bf16
                       unsigned short* __restrict__ S) {        // [M][128] bf16
  __shared__ __align__(16) float As[3][128 * 32];               // 3 x 16KB
  __shared__ __align__(16) unsigned short Bs[3][128 * 32];      // 3 x 8KB
  const int tid = threadIdx.x;
  const int lane = tid & 63;
  const int wv = tid >> 6;
  const int lr = lane & 15, lq = lane >> 4;
  const int bm0 = blockIdx.x * 128;
  const int wrow = wv * 32;

  f32x4 acc[2][8] = {};

#define STAGE(T, BUF)                                                          \
  do {                                                                         \
    _Pragma("unroll") for (int i = 0; i < 4; i++) {                            \
      int idx = i * 256 + tid;                                                 \
      int r = idx >> 3, c = idx & 7;                                           \
      int gr = bm0 + r; if (gr > M_N - 1) gr = M_N - 1;                        \
      const float* srcp = A + (size_t)gr * K_F + (T) * 32 + (c ^ (r & 7)) * 4; \
      __builtin_amdgcn_global_load_lds(                                        \
          (const __attribute__((address_space(1))) void*)srcp,                 \
          (__attribute__((address_space(3))) void*)&As[BUF][(i * 256 + wv * 64) * 4], \
          16, 0, 0);                                                           \
    }                                                                          \
    _Pragma("unroll") for (int i = 0; i < 2; i++) {                            \
      int idx = i * 256 + tid;                                                 \
      int n = idx >> 2, c = idx & 3;                                           \
      const unsigned short* srcb = Bt + (size_t)n * K_F + (T) * 32 + (c ^ (n & 3)) * 8; \
      __builtin_amdgcn_global_load_lds(                                        \
          (const __attribute__((address_space(1))) void*)srcb,                 \
          (__attribute__((address_space(3))) void*)&Bs[BUF][(i * 256 + wv * 64) * 8], \
          16, 0, 0);                                                           \
    }                                                                          \
  } while (0)

  STAGE(0, 0);
  STAGE(1, 1);

#pragma unroll
  for (int t = 0; t < 16; t++) {
    if (t < 15) asm volatile("s_waitcnt vmcnt(6)" ::: "memory");
    else        asm volatile("s_waitcnt vmcnt(0)" ::: "memory");
    __builtin_amdgcn_sched_barrier(0);
    __builtin_amdgcn_s_barrier();
    __builtin_amdgcn_sched_barrier(0);
    if (t < 14) {
      switch ((t + 2) % 3) {          // compile-time under full unroll
        case 0: STAGE(t + 2, 0); break;
        case 1: STAGE(t + 2, 1); break;
        default: STAGE(t + 2, 2); break;
      }
    }
    const int cb_ = t % 3;
    bf16x8 pb[8];
#pragma unroll
    for (int n = 0; n < 8; n++) {
      int r = n * 16 + lr;
      int cc = lq ^ (r & 3);
      pb[n] = *(const bf16x8*)&Bs[cb_][r * 32 + cc * 8];
    }
#pragma unroll
    for (int m = 0; m < 2; m++) {
      int R = wrow + m * 16 + lr;
      int cb = lq * 2, sw = R & 7;
      f32x4 f0 = *(const f32x4*)&As[cb_][R * 32 + ((cb) ^ sw) * 4];
      f32x4 f1 = *(const f32x4*)&As[cb_][R * 32 + ((cb + 1) ^ sw) * 4];
      uint4 u;
      u.x = pkbf(f0[0], f0[1]);
      u.y = pkbf(f0[2], f0[3]);
      u.z = pkbf(f1[0], f1[1]);
      u.w = pkbf(f1[2], f1[3]);
      bf16x8 af = *(bf16x8*)&u;
#pragma unroll
      for (int n = 0; n < 8; n++)
        acc[m][n] = __builtin_amdgcn_mfma_f32_16x16x32_bf16(af, pb[n], acc[m][n], 0, 0, 0);
    }
  }
#undef STAGE

  // epilogue: D layout col=lane&15, row=(lane>>4)*4+j  [measured m89]
#pragma unroll
  for (int m = 0; m < 2; m++)
#pragma unroll
    for (int j = 0; j < 4; j++) {
      int gr = bm0 + wrow + m * 16 + lq * 4 + j;
      if (gr < M_N) {
#pragma unroll
        for (int n = 0; n < 8; n++)
          S[(size_t)gr * N_F + n * 16 + lr] = f2bf(acc[m][n][j]);
      }
    }
}

// ---------- 3) bin edges by dst>>7 with per-block run reservation ----------
__global__ __launch_bounds__(512) void k_bin(const int* __restrict__ src,
                                             const int* __restrict__ dst,
                                             const float* __restrict__ w,
                                             int* __restrict__ gcur,
                                             uint2* __restrict__ ebin) {
  __shared__ int lh[NBUK];
  __shared__ int lb[NBUK];
  const int tid = threadIdx.x;
  const int e0 = blockIdx.x * EPB;
  for (int b = tid; b < NBUK; b += 512) lh[b] = 0;
  __syncthreads();
#pragma unroll
  for (int i = 0; i < EPB / 512; i++) {
    int e = e0 + i * 512 + tid;
    if (e < N_E) atomicAdd(&lh[dst[e] >> 7], 1);
  }
  __syncthreads();
  for (int b = tid; b < NBUK; b += 512) {
    int c = lh[b];
    lb[b] = c ? atomicAdd(&gcur[b], c) : 0;
    lh[b] = 0;                       // reuse as rank cursor
  }
  __syncthreads();
#pragma unroll
  for (int i = 0; i < EPB / 512; i++) {
    int e = e0 + i * 512 + tid;
    if (e < N_E) {
      int d = dst[e];
      int bk = d >> 7;
      int rank = atomicAdd(&lh[bk], 1);
      ebin[lb[bk] + rank] =
          make_uint2(((unsigned)(d & 127) << 17) | (unsigned)src[e],
                     __float_as_uint(w[e]));
    }
  }
}

// ---------- 4) fused bucket sort + SpMM gather + ReLU ----------
__device__ __forceinline__ void fma8(float* acc, float wgt, uint4 v) {
  acc[0] = fmaf(wgt, __uint_as_float(v.x << 16), acc[0]);
  acc[1] = fmaf(wgt, __uint_as_float(v.x & 0xFFFF0000u), acc[1]);
  acc[2] = fmaf(wgt, __uint_as_float(v.y << 16), acc[2]);
  acc[3] = fmaf(wgt, __uint_as_float(v.y & 0xFFFF0000u), acc[3]);
  acc[4] = fmaf(wgt, __uint_as_float(v.z << 16), acc[4]);
  acc[5] = fmaf(wgt, __uint_as_float(v.z & 0xFFFF0000u), acc[5]);
  acc[6] = fmaf(wgt, __uint_as_float(v.w << 16), acc[6]);
  acc[7] = fmaf(wgt, __uint_as_float(v.w & 0xFFFF0000u), acc[7]);
}

__global__ __launch_bounds__(512) void k_bspmm(const unsigned short* __restrict__ S,
                                               const int* __restrict__ gcur,
                                               const uint2* __restrict__ ebin,
                                               float* __restrict__ out) {
  __shared__ uint2 srt[CAP];                 // 20KB sorted edges
  __shared__ int hist[128], excl[129], cur[128];
  const int b = blockIdx.x;
  const int t = threadIdx.x;
  const int cnt = gcur[b] - b * CAP;
  const uint2* eb = ebin + (size_t)b * CAP;

  if (t < 128) hist[t] = 0;
  __syncthreads();

  // edges -> registers (static 5-slot, CAP/512 = 5)
  uint2 er[5];
  int have = 0;
#pragma unroll
  for (int j = 0; j < 5; j++) {
    int i = j * 512 + t;
    if (i < cnt) { er[j] = eb[i]; have = j + 1; }
  }
#pragma unroll
  for (int j = 0; j < 5; j++)
    if (j < have) atomicAdd(&hist[(er[j].x >> 17) & 127], 1);   // ds_add_u32
  __syncthreads();

  // exclusive scan over 128 counters
  if (t < 128) excl[t + 1] = hist[t];
  if (t == 0) excl[0] = 0;
  __syncthreads();
  for (int off = 1; off < 128; off <<= 1) {
    int v = 0;
    if (t < 128) {
      v = excl[t + 1];
      if (t + 1 > off) v += excl[t + 1 - off];
    }
    __syncthreads();
    if (t < 128) excl[t + 1] = v;
    __syncthreads();
  }
  if (t < 128) cur[t] = excl[t];
  __syncthreads();

  // scatter into sorted LDS array
#pragma unroll
  for (int j = 0; j < 5; j++)
    if (j < have) {
      int dl = (er[j].x >> 17) & 127;
      int r = atomicAdd(&cur[dl], 1);
      srt[r] = er[j];
    }
  __syncthreads();

  // gather: wave wv owns nodes [wv*16, +16)
  const int lane = t & 63, wv = t >> 6;
  const int g = lane >> 4;            // edge subgroup 0..3
  const int l = lane & 15;            // 16B chunk within the 256B row
  for (int nn = 0; nn < 16; nn++) {
    const int ln = wv * 16 + nn;      // local node
    const int s = excl[ln], e = excl[ln + 1];
    float acc[8] = {0.f, 0.f, 0.f, 0.f, 0.f, 0.f, 0.f, 0.f};
    int i = s + g;
    for (; i + 4 < e; i += 8) {       // 2 gathers in flight per group (8/wave)
      uint2 p0 = srt[i];
      uint2 p1 = srt[i + 4];
      uint4 v0 = *(const uint4*)(S + (size_t)(p0.x & 0x1FFFFu) * N_F + l * 8);
      uint4 v1 = *(const uint4*)(S + (size_t)(p1.x & 0x1FFFFu) * N_F + l * 8);
      fma8(acc, __uint_as_float(p0.y), v0);
      fma8(acc, __uint_as_float(p1.y), v1);
    }
    if (i < e) {
      uint2 p = srt[i];
      uint4 v = *(const uint4*)(S + (size_t)(p.x & 0x1FFFFu) * N_F + l * 8);
      fma8(acc, __uint_as_float(p.y), v);
    }
#pragma unroll
    for (int j = 0; j < 8; j++) {
      acc[j] += __shfl_xor(acc[j], 16, 64);
      acc[j] += __shfl_xor(acc[j], 32, 64);
      acc[j] = fmaxf(acc[j], 0.f);
    }
    const int node = b * 128 + ln;
    if (g < 2 && node < M_N) {
      float4 r = make_float4(acc[g * 4 + 0], acc[g * 4 + 1],
                             acc[g * 4 + 2], acc[g * 4 + 3]);
      *(float4*)(out + (size_t)node * N_F + l * 8 + g * 4) = r;
    }
  }
}

extern "C" void kernel_launch(void* const* d_in, const int* in_sizes, int n_in,
                              void* d_out, int out_size, void* d_ws, size_t ws_size,
                              hipStream_t stream) {
  const float* features = (const float*)d_in[0];
  const float* weight   = (const float*)d_in[1];
  const int* edge_src   = (const int*)d_in[2];
  const int* edge_dst   = (const int*)d_in[3];
  const float* edge_w   = (const float*)d_in[4];
  float* out = (float*)d_out;

  // workspace layout (256B-aligned chunks)
  char* ws = (char*)d_ws;
  size_t off = 0;
  unsigned short* support = (unsigned short*)(ws + off); off += (size_t)M_N * N_F * 2;   // 25.6MB
  unsigned short* wtb     = (unsigned short*)(ws + off); off += (size_t)N_F * K_F * 2;   // 128KB
  int* gcur   = (int*)(ws + off); off += 4096;
  uint2* ebin = (uint2*)(ws + off); off += ((size_t)NBUK * CAP + 64) * 8;                // ~16MB

  k_wt<<<256, 256, 0, stream>>>(weight, wtb, gcur);
  k_gemm<<<(M_N + 127) / 128, 256, 0, stream>>>(features, wtb, support);
  k_bin<<<(N_E + EPB - 1) / EPB, 512, 0, stream>>>(edge_src, edge_dst, edge_w, gcur, ebin);
  k_bspmm<<<NBUK, 512, 0, stream>>>(support, gcur, ebin, out);
}